// Round 1
// baseline (79.728 us; speedup 1.0000x reference)
//
#include <hip/hip_runtime.h>

// ConvDeepSet: B=8, N_IN=1024, N_OUT=4096, IN_CHANNELS=2, OUT_CHANNELS=64
//
// dens[b,m] = sum_n exp(-0.5*d(n,m)/s0^2)
// conv[b,m] = sum_n y[b,n]*exp(-0.5*d(n,m)/s1^2)
// out[b,m,o] = dens*W[o,0] + (conv/(dens+1e-8))*W[o,1] + b[o]
//
// One lane per target point m (t in registers), x/y streamed from LDS
// (wave-broadcast reads -> conflict-free). 4 waves/block each take a
// 256-long n-chunk; LDS cross-wave reduction; fused linear epilogue.

#define N_IN  1024
#define N_OUT 4096
#define OUTC  64

__global__ __launch_bounds__(256) void convdeepset_kernel(
    const float* __restrict__ x,     // [B, N_IN, 2]
    const float* __restrict__ y,     // [B, N_IN]
    const float* __restrict__ t,     // [B, N_OUT, 2]
    const float* __restrict__ sigma, // [2]
    const float* __restrict__ W,     // [64, 2]
    const float* __restrict__ bias,  // [64]
    float* __restrict__ out)         // [B, N_OUT, 64]
{
    __shared__ float2 xs[N_IN];          // 8 KB
    __shared__ float  ys[N_IN];          // 4 KB
    __shared__ float  dens_part[4 * 64]; // 1 KB
    __shared__ float  conv_part[4 * 64]; // 1 KB
    __shared__ float  dens_tot[64];
    __shared__ float  conv_tot[64];      // holds conv/(dens+eps)

    const int tid = threadIdx.x;
    const int b   = blockIdx.x >> 6;         // 64 m-tiles per batch
    const int m0  = (blockIdx.x & 63) << 6;  // this block's 64 target points

    // Stage this batch's x,y into LDS (coalesced float2 / float loads).
    const float2* xg = (const float2*)(x + (size_t)b * N_IN * 2);
    const float*  yg = y + (size_t)b * N_IN;
    for (int i = tid; i < N_IN; i += 256) {
        xs[i] = xg[i];
        ys[i] = yg[i];
    }

    // exp(-0.5*d/s^2) = exp2(k*d), k = -0.5*exp(-2*sigma)*log2(e)
    const float log2e = 1.44269504088896340736f;
    const float k0 = -0.5f * __expf(-2.0f * sigma[0]) * log2e;
    const float k1 = -0.5f * __expf(-2.0f * sigma[1]) * log2e;

    __syncthreads();

    const int wave = tid >> 6;
    const int lane = tid & 63;
    const int m    = m0 + lane;
    const float2 tv = ((const float2*)(t + ((size_t)b * N_OUT + m) * 2))[0];

    float dens = 0.f, conv = 0.f;
    const int nbeg = wave * (N_IN / 4);
    #pragma unroll 4
    for (int n = nbeg; n < nbeg + N_IN / 4; ++n) {
        float2 xv = xs[n];        // wave-broadcast LDS read
        float  yv = ys[n];
        float dx = xv.x - tv.x;
        float dy = xv.y - tv.y;
        float d  = dx * dx + dy * dy;
        dens += __builtin_amdgcn_exp2f(d * k0);
        conv += yv * __builtin_amdgcn_exp2f(d * k1);
    }
    dens_part[wave * 64 + lane] = dens;
    conv_part[wave * 64 + lane] = conv;
    __syncthreads();

    if (tid < 64) {
        float dt = dens_part[tid] + dens_part[64 + tid] +
                   dens_part[128 + tid] + dens_part[192 + tid];
        float ct = conv_part[tid] + conv_part[64 + tid] +
                   conv_part[128 + tid] + conv_part[192 + tid];
        dens_tot[tid] = dt;
        conv_tot[tid] = ct / (dt + 1e-8f);
    }
    __syncthreads();

    // Epilogue: 64 m x 64 o outputs. Lane -> o (coalesced stores),
    // each wave covers 16 m's; dens_tot/conv_tot reads are broadcasts.
    const int o = tid & 63;
    const int g = tid >> 6;
    const float w0 = W[o * 2 + 0];
    const float w1 = W[o * 2 + 1];
    const float bo = bias[o];
    float* outb = out + ((size_t)b * N_OUT + m0) * OUTC;
    #pragma unroll
    for (int i = 0; i < 16; ++i) {
        int mm = g * 16 + i;
        outb[mm * OUTC + o] = dens_tot[mm] * w0 + conv_tot[mm] * w1 + bo;
    }
}

extern "C" void kernel_launch(void* const* d_in, const int* in_sizes, int n_in,
                              void* d_out, int out_size, void* d_ws, size_t ws_size,
                              hipStream_t stream) {
    const float* x     = (const float*)d_in[0];
    const float* y     = (const float*)d_in[1];
    const float* t     = (const float*)d_in[2];
    const float* sigma = (const float*)d_in[3];
    const float* W     = (const float*)d_in[4];
    const float* bias  = (const float*)d_in[5];
    float* out = (float*)d_out;

    // 8 batches x (4096/64) m-tiles = 512 blocks, 256 threads each.
    convdeepset_kernel<<<dim3(512), dim3(256), 0, stream>>>(
        x, y, t, sigma, W, bias, out);
}

// Round 2
// 74.283 us; speedup vs baseline: 1.0733x; 1.0733x over previous
//
#include <hip/hip_runtime.h>

// ConvDeepSet: B=8, N_IN=1024, N_OUT=4096, OUT_CHANNELS=64
//
// dens[b,m] = sum_n exp(k0 * d(n,m)),  conv[b,m] = sum_n y[n] exp(k1 * d(n,m))
// out[b,m,o] = dens*W[o,0] + (conv/(dens+1e-8))*W[o,1] + b[o]
// k = -0.5*exp(-2*sigma)*log2(e), evaluated with exp2.
//
// Fast path (the actual data has sigma[0]==sigma[1] -> k0==k1): ONE exp per
// pair, coordinates pre-scaled by s=sqrt(-k0) so arg = -(dx^2+dy^2).
// Generic path stays correct: arg1 = arg0 * (k1/k0) (uniform ratio).
//
// Block: 1024 threads = 16 waves; covers 128 m (each lane 2 m's, stride 64).
// n-range split 16 ways (64 n / wave, read as 32 float4 = 2 n's per b128).
// Grid: 8 batches x 32 m-tiles = 256 blocks (1/CU, 4 waves/SIMD).

#define OUTC 64
#define MB   128

__global__ __launch_bounds__(1024) void convdeepset_kernel(
    const float* __restrict__ x,     // [B,1024,2]
    const float* __restrict__ y,     // [B,1024]
    const float* __restrict__ t,     // [B,4096,2]
    const float* __restrict__ sigma, // [2]
    const float* __restrict__ W,     // [64,2]
    const float* __restrict__ bias,  // [64]
    float* __restrict__ out)         // [B,4096,64]
{
    __shared__ float4 pk[512];           // 8 KB: (x0a,x1a,x0b,x1b) prescaled
    __shared__ float2 yy[512];           // 4 KB: (ya,yb)
    __shared__ float  dens_part[16*MB];  // 8 KB
    __shared__ float  conv_part[16*MB];  // 8 KB
    __shared__ float  sums[2*MB];
    __shared__ float  dens_tot[MB];
    __shared__ float  ratio[MB];

    const int tid = threadIdx.x;
    const int b   = blockIdx.x >> 5;         // 32 m-tiles per batch
    const int m0  = (blockIdx.x & 31) * MB;

    const float log2e = 1.44269504088896340736f;
    const float k0 = -0.5f * __expf(-2.0f * sigma[0]) * log2e;
    const float k1 = -0.5f * __expf(-2.0f * sigma[1]) * log2e;
    const float s0 = sqrtf(-k0);
    const float r  = k1 / k0;            // arg1 = arg0 * r (uniform)

    // Stage: first 512 threads load x pairs (prescaled), rest load y pairs.
    if (tid < 512) {
        const float4* xg = (const float4*)(x + (size_t)b * 2048);
        float4 xv = xg[tid];
        xv.x *= s0; xv.y *= s0; xv.z *= s0; xv.w *= s0;
        pk[tid] = xv;
    } else {
        const float2* yg = (const float2*)(y + (size_t)b * 1024);
        yy[tid - 512] = yg[tid - 512];
    }

    const int wave = tid >> 6;
    const int lane = tid & 63;
    const float2* tg = (const float2*)(t + ((size_t)b * 4096 + m0) * 2);
    const float2 ta = tg[lane];
    const float2 tb = tg[64 + lane];
    const float t0x = ta.x * s0, t0y = ta.y * s0;
    const float t1x = tb.x * s0, t1y = tb.y * s0;

    __syncthreads();

    float d0 = 0.f, c0 = 0.f, d1 = 0.f, c1 = 0.f;
    const int ibeg = wave * 32;          // 32 float4-iters = 64 n per wave

    if (r == 1.0f) {
        #pragma unroll 4
        for (int i = ibeg; i < ibeg + 32; ++i) {
            const float4 p  = pk[i];     // wave-broadcast b128
            const float2 yv = yy[i];
            {   // n=a, m=0
                float dx = p.x - t0x, dy = p.y - t0y;
                float e = __builtin_amdgcn_exp2f(fmaf(dx, -dx, -(dy * dy)));
                d0 += e; c0 = fmaf(yv.x, e, c0);
            }
            {   // n=a, m=1
                float dx = p.x - t1x, dy = p.y - t1y;
                float e = __builtin_amdgcn_exp2f(fmaf(dx, -dx, -(dy * dy)));
                d1 += e; c1 = fmaf(yv.x, e, c1);
            }
            {   // n=b, m=0
                float dx = p.z - t0x, dy = p.w - t0y;
                float e = __builtin_amdgcn_exp2f(fmaf(dx, -dx, -(dy * dy)));
                d0 += e; c0 = fmaf(yv.y, e, c0);
            }
            {   // n=b, m=1
                float dx = p.z - t1x, dy = p.w - t1y;
                float e = __builtin_amdgcn_exp2f(fmaf(dx, -dx, -(dy * dy)));
                d1 += e; c1 = fmaf(yv.y, e, c1);
            }
        }
    } else {
        #pragma unroll 2
        for (int i = ibeg; i < ibeg + 32; ++i) {
            const float4 p  = pk[i];
            const float2 yv = yy[i];
            {
                float dx = p.x - t0x, dy = p.y - t0y;
                float a  = fmaf(dx, -dx, -(dy * dy));
                d0 += __builtin_amdgcn_exp2f(a);
                c0 = fmaf(yv.x, __builtin_amdgcn_exp2f(a * r), c0);
            }
            {
                float dx = p.x - t1x, dy = p.y - t1y;
                float a  = fmaf(dx, -dx, -(dy * dy));
                d1 += __builtin_amdgcn_exp2f(a);
                c1 = fmaf(yv.x, __builtin_amdgcn_exp2f(a * r), c1);
            }
            {
                float dx = p.z - t0x, dy = p.w - t0y;
                float a  = fmaf(dx, -dx, -(dy * dy));
                d0 += __builtin_amdgcn_exp2f(a);
                c0 = fmaf(yv.y, __builtin_amdgcn_exp2f(a * r), c0);
            }
            {
                float dx = p.z - t1x, dy = p.w - t1y;
                float a  = fmaf(dx, -dx, -(dy * dy));
                d1 += __builtin_amdgcn_exp2f(a);
                c1 = fmaf(yv.y, __builtin_amdgcn_exp2f(a * r), c1);
            }
        }
    }

    dens_part[wave * MB + lane]      = d0;
    dens_part[wave * MB + 64 + lane] = d1;
    conv_part[wave * MB + lane]      = c0;
    conv_part[wave * MB + 64 + lane] = c1;
    __syncthreads();

    // Cross-wave reduce: 256 threads, each sums 16 partials for one (ch, m).
    if (tid < 256) {
        const int m = tid & (MB - 1);
        const float* src = (tid < MB) ? dens_part : conv_part;
        float s = 0.f;
        #pragma unroll
        for (int w = 0; w < 16; ++w) s += src[w * MB + m];
        sums[tid] = s;
    }
    __syncthreads();
    if (tid < MB) {
        float dt = sums[tid];
        dens_tot[tid] = dt;
        ratio[tid]    = sums[MB + tid] / (dt + 1e-8f);
    }
    __syncthreads();

    // Epilogue: 128 m x 64 o; lane->o (coalesced), 16 groups x 8 m each.
    const int o = tid & 63;
    const int g = tid >> 6;
    const float w0 = W[o * 2 + 0];
    const float w1 = W[o * 2 + 1];
    const float bo = bias[o];
    float* outb = out + ((size_t)b * 4096 + m0) * OUTC;
    #pragma unroll
    for (int i = 0; i < 8; ++i) {
        int mm = g * 8 + i;
        outb[mm * OUTC + o] = fmaf(dens_tot[mm], w0, fmaf(ratio[mm], w1, bo));
    }
}

extern "C" void kernel_launch(void* const* d_in, const int* in_sizes, int n_in,
                              void* d_out, int out_size, void* d_ws, size_t ws_size,
                              hipStream_t stream) {
    const float* x     = (const float*)d_in[0];
    const float* y     = (const float*)d_in[1];
    const float* t     = (const float*)d_in[2];
    const float* sigma = (const float*)d_in[3];
    const float* W     = (const float*)d_in[4];
    const float* bias  = (const float*)d_in[5];
    float* out = (float*)d_out;

    convdeepset_kernel<<<dim3(256), dim3(1024), 0, stream>>>(
        x, y, t, sigma, W, bias, out);
}